// Round 7
// baseline (1768.698 us; speedup 1.0000x reference)
//
#include <hip/hip_runtime.h>

// PosLearnedSimulator — split-bf16 MFMA, 3-deep async panel pipeline (counted vmcnt),
// transposed coalesced epilogues, CSR aggregation.
// N=10000 nodes, E=80000 edges, H=128, L=10 layers.

#define NH  128
#define TPB 256

typedef unsigned short u16;
typedef unsigned int   u32;
using s8v = __attribute__((ext_vector_type(8))) short;   // 8 bf16 (4 VGPR)
using f4v = __attribute__((ext_vector_type(4))) float;   // MFMA accumulator

// ---------------- bf16 split helpers ----------------

__device__ __forceinline__ u16 bf_hi(float v) {
  u32 u = __float_as_uint(v);
  return (u16)((u + 0x7FFFu + ((u >> 16) & 1u)) >> 16);   // RTNE
}
__device__ __forceinline__ float bf_f(u16 h) { return __uint_as_float((u32)h << 16); }
__device__ __forceinline__ void split2(float v, u16& h, u16& l) {
  h = bf_hi(v); l = bf_hi(v - bf_f(h));
}
__device__ __forceinline__ void split8(const float* v, s8v& fh, s8v& fl) {
  union { u32 u[4]; s8v s; } H, L;
  #pragma unroll
  for (int i = 0; i < 4; ++i) {
    u16 h0, l0, h1, l1;
    split2(v[2*i], h0, l0); split2(v[2*i+1], h1, l1);
    H.u[i] = (u32)h0 | ((u32)h1 << 16);
    L.u[i] = (u32)l0 | ((u32)l1 << 16);
  }
  fh = H.s; fl = L.s;
}

// 3-term split-bf16 MFMA: C += Ah*Bh + Ah*Bl + Al*Bh
__device__ __forceinline__ f4v mfma3(s8v ah, s8v al, s8v bh, s8v bl, f4v c) {
  c = __builtin_amdgcn_mfma_f32_16x16x32_bf16(ah, bh, c, 0, 0, 0);
  c = __builtin_amdgcn_mfma_f32_16x16x32_bf16(ah, bl, c, 0, 0, 0);
  c = __builtin_amdgcn_mfma_f32_16x16x32_bf16(al, bh, c, 0, 0, 0);
  return c;
}

__device__ __forceinline__ float lrelu(float v) { return v > 0.f ? v : 0.01f * v; }

__device__ __forceinline__ void pack2(f4v a, u32& w0, u32& w1, u32& v0, u32& v1) {
  u16 h[4], lo[4];
  #pragma unroll
  for (int r = 0; r < 4; ++r) { const float x = lrelu(a[r]); split2(x, h[r], lo[r]); }
  w0 = (u32)h[0]  | ((u32)h[1]  << 16); w1 = (u32)h[2]  | ((u32)h[3]  << 16);
  v0 = (u32)lo[0] | ((u32)lo[1] << 16); v1 = (u32)lo[2] | ((u32)lo[3] << 16);
}

__device__ __forceinline__ void trans_frag(f4v a0, f4v a1, int srcA, int srcB, bool sel1,
                                           s8v& fh, s8v& fl) {
  u32 h00,h01,l00,l01, h10,h11,l10,l11;
  pack2(a0, h00,h01,l00,l01);
  pack2(a1, h10,h11,l10,l11);
  union { u32 u[4]; s8v s; } H, L;
  u32 x, y;
  x = __shfl((int)h00, srcA); y = __shfl((int)h10, srcA); H.u[0] = sel1 ? y : x;
  x = __shfl((int)h01, srcA); y = __shfl((int)h11, srcA); H.u[1] = sel1 ? y : x;
  x = __shfl((int)h00, srcB); y = __shfl((int)h10, srcB); H.u[2] = sel1 ? y : x;
  x = __shfl((int)h01, srcB); y = __shfl((int)h11, srcB); H.u[3] = sel1 ? y : x;
  x = __shfl((int)l00, srcA); y = __shfl((int)l10, srcA); L.u[0] = sel1 ? y : x;
  x = __shfl((int)l01, srcA); y = __shfl((int)l11, srcA); L.u[1] = sel1 ? y : x;
  x = __shfl((int)l00, srcB); y = __shfl((int)l10, srcB); L.u[2] = sel1 ? y : x;
  x = __shfl((int)l01, srcB); y = __shfl((int)l11, srcB); L.u[3] = sel1 ? y : x;
  fh = H.s; fl = L.s;
}

// ---------------- async LDS weight-panel staging (global_load_lds) ----------------
// Panel: [128 rows][32 k] u16 per plane (hi at 0, lo at +4096 u16).
// Physical 16B chunk of (row, logical chunk g): slot = g ^ ((row>>1)&3); LDS dest LINEAR
// (wave-uniform base + lane*16B), source pre-swizzled.

__device__ __forceinline__ void gl_lds16(const void* g, void* l) {
  __builtin_amdgcn_global_load_lds(
      (const __attribute__((address_space(1))) void*)g,
      (__attribute__((address_space(3))) void*)l, 16, 0, 0);
}

// 256-thread variant: 4 loads/thread/panel
__device__ __forceinline__ void stage_async(const u16* __restrict__ base, int KW, int LO,
                                            int col, int w, int l, u16* wb) {
  const int glog8 = ((l & 3) ^ ((l >> 3) & 3)) * 8;
  #pragma unroll
  for (int i = 0; i < 2; ++i) {
    const int t2u = (w * 2 + i) * 64;
    const u16* gp = base + (size_t)((t2u + l) >> 2) * KW + col + glog8;
    gl_lds16(gp,      wb + (size_t)t2u * 8);
    gl_lds16(gp + LO, wb + 4096 + (size_t)t2u * 8);
  }
}

// 128-thread variant: 8 loads/thread/panel
__device__ __forceinline__ void stage_async_n(const u16* __restrict__ base, int KW, int LO,
                                              int col, int w, int l, u16* wb) {
  const int glog8 = ((l & 3) ^ ((l >> 3) & 3)) * 8;
  #pragma unroll
  for (int i = 0; i < 4; ++i) {
    const int t2u = (w * 4 + i) * 64;
    const u16* gp = base + (size_t)((t2u + l) >> 2) * KW + col + glog8;
    gl_lds16(gp,      wb + (size_t)t2u * 8);
    gl_lds16(gp + 4096 + (size_t)0, (void*)0);  // placeholder removed below
  }
}

// NOTE: the placeholder line above is never used; real body follows.
__device__ __forceinline__ void stage_async_node(const u16* __restrict__ base, int KW, int LO,
                                                 int col, int w, int l, u16* wb) {
  const int glog8 = ((l & 3) ^ ((l >> 3) & 3)) * 8;
  #pragma unroll
  for (int i = 0; i < 4; ++i) {
    const int t2u = (w * 4 + i) * 64;
    const u16* gp = base + (size_t)((t2u + l) >> 2) * KW + col + glog8;
    gl_lds16(gp,      wb + (size_t)t2u * 8);
    gl_lds16(gp + LO, wb + 4096 + (size_t)t2u * 8);
  }
}

__device__ __forceinline__ void wfrag(const u16* panel, int tt, int c, int gsw, s8v& wh, s8v& wl) {
  const u16* p = panel + (16*tt + c) * 32 + gsw * 8;
  wh = *(const s8v*)p;
  wl = *(const s8v*)(p + 4096);
}

// end-of-pass sync: counted vmcnt keeps next-next panel in flight across the barrier
#define PASS_SYNC_MSG(p, LAST) \
  do { \
    if ((p) <= (LAST) - 2) { asm volatile("s_waitcnt vmcnt(4)" ::: "memory"); } \
    else if ((p) == (LAST) - 1) { asm volatile("s_waitcnt vmcnt(0)" ::: "memory"); } \
    __builtin_amdgcn_s_barrier(); \
    __builtin_amdgcn_sched_barrier(0); \
  } while (0)

#define PASS_SYNC_NODE(p, LAST) \
  do { \
    if ((p) <= (LAST) - 2) { asm volatile("s_waitcnt vmcnt(8)" ::: "memory"); } \
    else if ((p) == (LAST) - 1) { asm volatile("s_waitcnt vmcnt(0)" ::: "memory"); } \
    __builtin_amdgcn_s_barrier(); \
    __builtin_amdgcn_sched_barrier(0); \
  } while (0)

// ---------------- weight prep: transpose + bf16 split ----------------
#define ME1_OFF 0
#define ME2_OFF 983040
#define ME3_OFF 1310720
#define MN1_OFF 1638400
#define MN2_OFF 2293760
#define MN3_OFF 2621440
#define WT_TOTAL 2949120
#define PREP_ELEMS 1474560

__global__ void __launch_bounds__(256) k_prep(
    const float* __restrict__ meW1, const float* __restrict__ meW2, const float* __restrict__ meW3,
    const float* __restrict__ mnW1, const float* __restrict__ mnW2, const float* __restrict__ mnW3,
    u16* __restrict__ wt) {
  const int id = blockIdx.x * 256 + threadIdx.x;
  if (id >= PREP_ELEMS) return;
  const int l = id / 147456;
  const int rem = id % 147456;
  const float* src; u16* dh; int K, loc;
  if (rem < 49152)       { loc = rem;          K = 384; src = meW1 + (size_t)l*49152; dh = wt + ME1_OFF + (size_t)l*98304; }
  else if (rem < 65536)  { loc = rem - 49152;  K = 128; src = meW2 + (size_t)l*16384; dh = wt + ME2_OFF + (size_t)l*32768; }
  else if (rem < 81920)  { loc = rem - 65536;  K = 128; src = meW3 + (size_t)l*16384; dh = wt + ME3_OFF + (size_t)l*32768; }
  else if (rem < 114688) { loc = rem - 81920;  K = 256; src = mnW1 + (size_t)l*32768; dh = wt + MN1_OFF + (size_t)l*65536; }
  else if (rem < 131072) { loc = rem - 114688; K = 128; src = mnW2 + (size_t)l*16384; dh = wt + MN2_OFF + (size_t)l*32768; }
  else                   { loc = rem - 131072; K = 128; src = mnW3 + (size_t)l*16384; dh = wt + MN3_OFF + (size_t)l*32768; }
  const int n = loc / K, k = loc % K;
  const float v = src[(size_t)k * NH + n];
  u16 h, lo; split2(v, h, lo);
  dh[(size_t)n * K + k] = h;
  dh[(size_t)NH * K + (size_t)n * K + k] = lo;
}

// ---------------- CSR build ----------------

__global__ void __launch_bounds__(256) k_deg(const int* __restrict__ dst, int* __restrict__ cnt, int E) {
  const int e = blockIdx.x * 256 + threadIdx.x;
  if (e < E) atomicAdd(&cnt[dst[e]], 1);
}

__global__ void __launch_bounds__(256) k_scan(int* __restrict__ cur, int* __restrict__ off, int n, int E) {
  __shared__ int ps[256];
  const int t = threadIdx.x;
  const int chunk = (n + 255) / 256;
  const int b0 = t * chunk;
  int s = 0;
  for (int j = 0; j < chunk; ++j) { const int r = b0 + j; if (r < n) s += cur[r]; }
  ps[t] = s; __syncthreads();
  for (int d = 1; d < 256; d <<= 1) {
    const int v = (t >= d) ? ps[t - d] : 0; __syncthreads();
    ps[t] += v; __syncthreads();
  }
  int run = ps[t] - s;
  for (int j = 0; j < chunk; ++j) {
    const int r = b0 + j;
    if (r < n) { const int d = cur[r]; off[r] = run; cur[r] = run; run += d; }
  }
  if (t == 0) off[n] = E;
}

__global__ void __launch_bounds__(256) k_fill(const int* __restrict__ dst, int* __restrict__ cur,
                                              int* __restrict__ csr, int E) {
  const int e = blockIdx.x * 256 + threadIdx.x;
  if (e < E) { const int p = atomicAdd(&cur[dst[e]], 1); csr[p] = e; }
}

// ---------------- fp32 helpers for one-shot kernels (enc/dec) ----------------

__device__ __forceinline__ int swzB(int c) { return c ^ ((c >> 3) & 1); }
__device__ __forceinline__ void fma8(float* a, float s, const float4 b0, const float4 b1) {
  a[0] += s * b0.x; a[1] += s * b0.y; a[2] += s * b0.z; a[3] += s * b0.w;
  a[4] += s * b1.x; a[5] += s * b1.y; a[6] += s * b1.z; a[7] += s * b1.w;
}

template<int RB>
__device__ __forceinline__ void stage_rows128(
    const float* __restrict__ src, int row_base, int nmax, float* As, int t) {
  const int c = t & 31;
  for (int e = t >> 5; e < RB; e += 8) {
    int r = row_base + e; if (r >= nmax) r = nmax - 1;
    const float4 v = reinterpret_cast<const float4*>(src + (size_t)r * NH)[c];
    reinterpret_cast<float4*>(As)[e * 32 + (c ^ ((e >> 2) & 7))] = v;
  }
}

template<int RB>
__device__ __forceinline__ void stage_smallK(
    const float* __restrict__ src, const int* __restrict__ ridx,
    int row_base, int nmax, int F, float* As, int t) {
  for (int i = t; i < RB * F; i += TPB) {
    const int e = i / F, f = i - e * F;
    int r;
    if (ridx) r = ridx[e];
    else { r = row_base + e; if (r >= nmax) r = nmax - 1; }
    As[e * NH + ((((f >> 2) ^ ((e >> 2) & 7)) << 2) | (f & 3))] = src[(size_t)r * F + f];
  }
}

template<int AR>
__device__ __forceinline__ void init_acc(const float* __restrict__ b, float acc[AR][8], int t) {
  const int o0 = (t >> 4) * 8;
  const float4 c0 = *reinterpret_cast<const float4*>(b + o0);
  const float4 c1 = *reinterpret_cast<const float4*>(b + o0 + 4);
  #pragma unroll
  for (int i = 0; i < AR; ++i) {
    acc[i][0] = c0.x; acc[i][1] = c0.y; acc[i][2] = c0.z; acc[i][3] = c0.w;
    acc[i][4] = c1.x; acc[i][5] = c1.y; acc[i][6] = c1.z; acc[i][7] = c1.w;
  }
}

template<int AR>
__device__ __forceinline__ void gemm_block(
    const float* __restrict__ W, int Kpart,
    const float* As, float* Bs, float acc[AR][8], int t) {
  const int e0  = (t & 15) * AR;
  const int g   = t >> 4;
  const int ob0 = swzB(g * 2) * 4;
  const int ob1 = swzB(g * 2 + 1) * 4;
  int sr[AR];
  #pragma unroll
  for (int i = 0; i < AR; ++i) sr[i] = ((e0 + i) >> 2) & 7;
  for (int sub = 0; sub < Kpart; sub += 32) {
    int kmax = Kpart - sub; if (kmax > 32) kmax = 32;
    __syncthreads();
    {
      const int r  = t >> 3;
      const int cb = (t & 7) * 4;
      if (r < kmax) {
        const float4* s4 = reinterpret_cast<const float4*>(W + (size_t)(sub + r) * NH) + cb;
        #pragma unroll
        for (int j = 0; j < 4; ++j)
          *reinterpret_cast<float4*>(Bs + r * NH + swzB(cb + j) * 4) = s4[j];
      }
    }
    __syncthreads();
    if (kmax == 32) {
      #pragma unroll
      for (int k4 = 0; k4 < 8; ++k4) {
        const int gch = (sub >> 2) + k4;
        float4 aa[AR];
        #pragma unroll
        for (int i = 0; i < AR; ++i)
          aa[i] = reinterpret_cast<const float4*>(As)[(e0 + i) * 32 + (gch ^ sr[i])];
        #pragma unroll
        for (int kk = 0; kk < 4; ++kk) {
          const int k = k4 * 4 + kk;
          const float4 b0 = *reinterpret_cast<const float4*>(Bs + k * NH + ob0);
          const float4 b1 = *reinterpret_cast<const float4*>(Bs + k * NH + ob1);
          #pragma unroll
          for (int i = 0; i < AR; ++i) {
            const float a = (kk == 0) ? aa[i].x : (kk == 1) ? aa[i].y : (kk == 2) ? aa[i].z : aa[i].w;
            fma8(acc[i], a, b0, b1);
          }
        }
      }
    } else {
      for (int k = 0; k < kmax; ++k) {
        const int kk = sub + k;
        const float4 b0 = *reinterpret_cast<const float4*>(Bs + k * NH + ob0);
        const float4 b1 = *reinterpret_cast<const float4*>(Bs + k * NH + ob1);
        #pragma unroll
        for (int i = 0; i < AR; ++i) {
          const float a = As[(e0 + i) * NH + ((((kk >> 2) ^ sr[i]) << 2) | (kk & 3))];
          fma8(acc[i], a, b0, b1);
        }
      }
    }
  }
}

template<int AR, bool ACT>
__device__ __forceinline__ void act_store(float* As, float acc[AR][8], int t) {
  const int e0 = (t & 15) * AR;
  const int g  = t >> 4;
  __syncthreads();
  #pragma unroll
  for (int i = 0; i < AR; ++i) {
    const int r = e0 + i;
    const int s = (r >> 2) & 7;
    float v[8];
    #pragma unroll
    for (int j = 0; j < 8; ++j) v[j] = ACT ? lrelu(acc[i][j]) : acc[i][j];
    float4 w0 = {v[0], v[1], v[2], v[3]};
    float4 w1 = {v[4], v[5], v[6], v[7]};
    reinterpret_cast<float4*>(As + r * NH)[(g * 2)     ^ s] = w0;
    reinterpret_cast<float4*>(As + r * NH)[(g * 2 + 1) ^ s] = w1;
  }
  __syncthreads();
}

// ---------------- encoders / decoder (fp32, one-shot) ----------------

__global__ void __launch_bounds__(TPB) k_enc_node(
    const int* __restrict__ xt, const float* __restrict__ embed,
    const float* __restrict__ W1, const float* __restrict__ b1,
    const float* __restrict__ W2, const float* __restrict__ b2,
    const float* __restrict__ W3, const float* __restrict__ b3,
    float* __restrict__ node, int n) {
  constexpr int RB = 32, AR = 2;
  __shared__ float As[RB * NH];
  __shared__ float Bs[32 * NH];
  __shared__ int rid[RB];
  const int t = threadIdx.x;
  const int base = blockIdx.x * RB;
  if (t < RB) { int r = base + t; if (r >= n) r = n - 1; rid[t] = xt[r]; }
  __syncthreads();
  stage_smallK<RB>(embed, rid, 0, 2, 7, As, t);
  float acc[AR][8];
  init_acc<AR>(b1, acc, t);
  gemm_block<AR>(W1, 7, As, Bs, acc, t);
  act_store<AR, true>(As, acc, t);
  init_acc<AR>(b2, acc, t);
  gemm_block<AR>(W2, NH, As, Bs, acc, t);
  act_store<AR, true>(As, acc, t);
  init_acc<AR>(b3, acc, t);
  gemm_block<AR>(W3, NH, As, Bs, acc, t);
  const int e0 = (t & 15) * AR, o0 = (t >> 4) * 8;
  #pragma unroll
  for (int i = 0; i < AR; ++i) {
    const int r = base + e0 + i;
    if (r < n) {
      float4 v0 = {acc[i][0], acc[i][1], acc[i][2], acc[i][3]};
      float4 v1 = {acc[i][4], acc[i][5], acc[i][6], acc[i][7]};
      float4* p = reinterpret_cast<float4*>(node + (size_t)r * NH + o0);
      p[0] = v0; p[1] = v1;
    }
  }
}

__global__ void __launch_bounds__(TPB) k_enc_edge(
    const float* __restrict__ ea,
    const float* __restrict__ W1, const float* __restrict__ b1,
    const float* __restrict__ W2, const float* __restrict__ b2,
    const float* __restrict__ W3, const float* __restrict__ b3,
    float* __restrict__ edge, int nE) {
  constexpr int RB = 64, AR = 4;
  __shared__ float As[RB * NH];
  __shared__ float Bs[32 * NH];
  const int t = threadIdx.x;
  const int base = blockIdx.x * RB;
  stage_smallK<RB>(ea, nullptr, base, nE, 21, As, t);
  float acc[AR][8];
  init_acc<AR>(b1, acc, t);
  gemm_block<AR>(W1, 21, As, Bs, acc, t);
  act_store<AR, true>(As, acc, t);
  init_acc<AR>(b2, acc, t);
  gemm_block<AR>(W2, NH, As, Bs, acc, t);
  act_store<AR, true>(As, acc, t);
  init_acc<AR>(b3, acc, t);
  gemm_block<AR>(W3, NH, As, Bs, acc, t);
  const int e0 = (t & 15) * AR, o0 = (t >> 4) * 8;
  #pragma unroll
  for (int i = 0; i < AR; ++i) {
    const int r = base + e0 + i;
    if (r < nE) {
      float4 v0 = {acc[i][0], acc[i][1], acc[i][2], acc[i][3]};
      float4 v1 = {acc[i][4], acc[i][5], acc[i][6], acc[i][7]};
      float4* p = reinterpret_cast<float4*>(edge + (size_t)r * NH + o0);
      p[0] = v0; p[1] = v1;
    }
  }
}

__global__ void __launch_bounds__(TPB) k_dec(
    const float* __restrict__ node,
    const float* __restrict__ W1, const float* __restrict__ b1,
    const float* __restrict__ W2, const float* __restrict__ b2,
    const float* __restrict__ W3, const float* __restrict__ b3,
    float* __restrict__ out, int n) {
  constexpr int RB = 32, AR = 2;
  __shared__ float As[RB * NH];
  __shared__ float Bs[32 * NH];
  const int t = threadIdx.x;
  const int base = blockIdx.x * RB;
  stage_rows128<RB>(node, base, n, As, t);
  float acc[AR][8];
  init_acc<AR>(b1, acc, t);
  gemm_block<AR>(W1, NH, As, Bs, acc, t);
  act_store<AR, true>(As, acc, t);
  init_acc<AR>(b2, acc, t);
  gemm_block<AR>(W2, NH, As, Bs, acc, t);
  act_store<AR, true>(As, acc, t);
  if (t < RB * 2) {
    const int e = t >> 1, oc = t & 1;
    const int r = base + e;
    if (r < n) {
      const int s = (e >> 2) & 7;
      float sum = b3[oc];
      #pragma unroll 8
      for (int k = 0; k < NH; ++k)
        sum += As[e * NH + ((((k >> 2) ^ s) << 2) | (k & 3))] * W3[k * 2 + oc];
      out[(size_t)r * 2 + oc] = sum;
    }
  }
}

// ---------------- MFMA message kernel (v5: 3-deep counted-vmcnt pipeline) ----------------
__device__ __forceinline__ void msg_stage(int p, const u16* wt1, const u16* wt2, const u16* wt3,
                                          int w, int l, u16* dst) {
  if (p < 12)      stage_async(wt1, 384, 49152, p * 32, w, l, dst);
  else if (p < 16) stage_async(wt2, 128, 16384, (p - 12) * 32, w, l, dst);
  else             stage_async(wt3, 128, 16384, (p - 16) * 32, w, l, dst);
}

__global__ void __launch_bounds__(TPB) k_msg_mm(
    const int* __restrict__ ei, const float* __restrict__ node,
    float* __restrict__ edge, const float* __restrict__ dist, float* __restrict__ mw,
    const u16* __restrict__ wt1, const u16* __restrict__ wt2, const u16* __restrict__ wt3,
    const float* __restrict__ b1, const float* __restrict__ b2, const float* __restrict__ b3,
    int E) {
  __shared__ u16 wbuf[3][8192];
  const int t = threadIdx.x, w = t >> 6, l = t & 63, c = l & 15, g = l >> 4;
  const int gsw = g ^ ((c >> 1) & 3);
  const int wbase = blockIdx.x * 128 + w * 32;
  int e0 = wbase + c, e1 = wbase + 16 + c;
  if (e0 >= E) e0 = E - 1;
  if (e1 >= E) e1 = E - 1;
  const int sj0 = ei[e0], di0 = ei[E + e0];
  const int sj1 = ei[e1], di1 = ei[E + e1];

  const float* ap0[3] = { node + (size_t)di0 * NH, node + (size_t)sj0 * NH, edge + (size_t)e0 * NH };
  const float* ap1[3] = { node + (size_t)di1 * NH, node + (size_t)sj1 * NH, edge + (size_t)e1 * NH };

  // acts for pass 0, then panels 0 and 1 async
  float4 aC0 = *(const float4*)(ap0[0] + g*8);
  float4 aC1 = *(const float4*)(ap0[0] + g*8 + 4);
  float4 aC2 = *(const float4*)(ap1[0] + g*8);
  float4 aC3 = *(const float4*)(ap1[0] + g*8 + 4);
  stage_async(wt1, 384, 49152, 0,  w, l, wbuf[0]);
  stage_async(wt1, 384, 49152, 32, w, l, wbuf[1]);

  f4v acc1a[8], acc1b[8];
  #pragma unroll
  for (int tt = 0; tt < 8; ++tt) {
    const float4 bb = *(const float4*)(b1 + 16*tt + 4*g);
    acc1a[tt] = f4v{bb.x, bb.y, bb.z, bb.w};
    acc1b[tt] = acc1a[tt];
  }
  __syncthreads();                       // prologue: full drain (panels 0,1 resident)

  const int srcA = ((g & 1) * 2) * 16 + c, srcB = srcA + 16;
  const bool sel1 = (g >> 1) != 0;

  // ---- layer 1 (transposed): global passes 0..11
  #pragma unroll
  for (int p = 0; p < 12; ++p) {
    float4 aN0, aN1, aN2, aN3;
    if (p < 11) {                        // acts for p+1 (issued before stage -> older)
      const int pt = (p + 1) >> 2, kn = (p + 1) & 3;
      aN0 = *(const float4*)(ap0[pt] + kn*32 + g*8);
      aN1 = *(const float4*)(ap0[pt] + kn*32 + g*8 + 4);
      aN2 = *(const float4*)(ap1[pt] + kn*32 + g*8);
      aN3 = *(const float4*)(ap1[pt] + kn*32 + g*8 + 4);
    }
    msg_stage(p + 2, wt1, wt2, wt3, w, l, wbuf[(p + 2) % 3]);
    s8v h0, lo0, h1, lo1;
    { float v[8];
      *(float4*)v = aC0; *(float4*)(v + 4) = aC1; split8(v, h0, lo0);
      *(float4*)v = aC2; *(float4*)(v + 4) = aC3; split8(v, h1, lo1); }
    const u16* panel = wbuf[p % 3];
    __builtin_amdgcn_s_setprio(1);
    #pragma unroll
    for (int tt = 0; tt < 8; ++tt) {
      s8v wh, wl; wfrag(panel, tt, c, gsw, wh, wl);
      acc1a[tt] = mfma3(wh, wl, h0, lo0, acc1a[tt]);
      acc1b[tt] = mfma3(wh, wl, h1, lo1, acc1b[tt]);
    }
    __builtin_amdgcn_s_setprio(0);
    PASS_SYNC_MSG(p, 19);
    if (p < 11) { aC0 = aN0; aC1 = aN1; aC2 = aN2; aC3 = aN3; }
  }

  // ---- layer 2 (transposed): global passes 12..15
  f4v acc2a[8], acc2b[8];
  #pragma unroll
  for (int tt = 0; tt < 8; ++tt) {
    const float4 bb = *(const float4*)(b2 + 16*tt + 4*g);
    acc2a[tt] = f4v{bb.x, bb.y, bb.z, bb.w};
    acc2b[tt] = acc2a[tt];
  }
  #pragma unroll
  for (int kc = 0; kc < 4; ++kc) {
    const int p = 12 + kc;
    msg_stage(p + 2, wt1, wt2, wt3, w, l, wbuf[(p + 2) % 3]);
    s8v h0, lo0, h1, lo1;
    trans_frag(acc1a[2*kc], acc1a[2*kc+1], srcA, srcB, sel1, h0, lo0);
    trans_frag(acc1b[2*kc], acc1b[2*kc+1], srcA, srcB, sel1, h1, lo1);
    const u16* panel = wbuf[p % 3];
    __builtin_amdgcn_s_setprio(1);
    #pragma unroll
    for (int tt = 0; tt < 8; ++tt) {
      s8v wh, wl; wfrag(panel, tt, c, gsw, wh, wl);
      acc2a[tt] = mfma3(wh, wl, h0, lo0, acc2a[tt]);
      acc2b[tt] = mfma3(wh, wl, h1, lo1, acc2b[tt]);
    }
    __builtin_amdgcn_s_setprio(0);
    PASS_SYNC_MSG(p, 19);
  }

  // ---- layer 3 (natural): global passes 16..19
  f4v acc3a[8], acc3b[8];
  #pragma unroll
  for (int tt = 0; tt < 8; ++tt) {
    const float bv = b3[16*tt + c];
    acc3a[tt] = f4v{bv, bv, bv, bv};
    acc3b[tt] = acc3a[tt];
  }
  #pragma unroll
  for (int kc = 0; kc < 4; ++kc) {
    const int p = 16 + kc;
    if (kc < 2) msg_stage(p + 2, wt1, wt2, wt3, w, l, wbuf[(p + 2) % 3]);
    s8v h0, lo0, h1, lo1;
    trans_frag(acc2a[2*kc], acc2a[2*kc+1], srcA, srcB, sel1, h0, lo0);
    trans_frag(acc2b[2*kc], acc2b[2*kc+1], srcA, srcB, sel1, h1, lo1);
    const u16* panel = wbuf[p % 3];
    __builtin_amdgcn_s_setprio(1);
    #pragma unroll
    for (int tt = 0; tt < 8; ++tt) {
      s8v wh, wl; wfrag(panel, tt, c, gsw, wh, wl);
      acc3a[tt] = mfma3(h0, lo0, wh, wl, acc3a[tt]);
      acc3b[tt] = mfma3(h1, lo1, wh, wl, acc3b[tt]);
    }
    __builtin_amdgcn_s_setprio(0);
    if (p < 19) PASS_SYNC_MSG(p, 19);
  }
  __syncthreads();                       // wbuf free for transpose scratch

  // ---- transposed epilogue: m through LDS -> coalesced float4 RMW/stores
  float* slice = ((float*)&wbuf[0][0]) + w * 2048;      // per-wave 16 rows x 128 f32
  const int rowr = l >> 2, q = l & 3;
  #pragma unroll
  for (int ch = 0; ch < 2; ++ch) {
    #pragma unroll
    for (int tt = 0; tt < 8; ++tt)
      #pragma unroll
      for (int r = 0; r < 4; ++r) {
        const int row = 4*g + r;
        slice[row*128 + (((tt ^ (row & 7)) << 4) | c)] = ch ? acc3b[tt][r] : acc3a[tt][r];
      }
    const int e = wbase + ch * 16 + rowr;
    if (e < E) {
      const float dw = dist[e];
      float* ep = edge + (size_t)e * NH + q * 32;
      float* mp = mw   + (size_t)e * NH + q * 32;
      #pragma unroll
      for (int j = 0; j < 2; ++j)
        #pragma unroll
        for (int v = 0; v < 4; ++v) {
          const float4 m4 = *(const float4*)&slice[rowr*128 + (((2*q + j) ^ (rowr & 7)) << 4) + v*4];
          float4 x = *(const float4*)(ep + j*16 + v*4);
          x.x += m4.x; x.y += m4.y; x.z += m4.z; x.w += m4.w;
          *(float4*)(ep + j*16 + v*4) = x;
          float4 mm = {m4.x*dw, m4.y*dw, m4.z*dw, m4.w*dw};
          *(float4*)(mp + j*16 + v*4) = mm;
        }
    }
    if (ch == 0) __syncthreads();
  }
}

// ---------------- MFMA node-update kernel (v5: 128 threads, 32 nodes, 3-deep pipeline) ----------------
__device__ __forceinline__ void node_stage(int p, const u16* wt1, const u16* wt2, const u16* wt3,
                                           int w, int l, u16* dst) {
  if (p < 8)       stage_async_node(wt1, 256, 32768, p * 32, w, l, dst);
  else if (p < 12) stage_async_node(wt2, 128, 16384, (p - 8) * 32, w, l, dst);
  else             stage_async_node(wt3, 128, 16384, (p - 12) * 32, w, l, dst);
}

__global__ void __launch_bounds__(128) k_node_mm(
    const int* __restrict__ off, const int* __restrict__ csr, const float* __restrict__ mw,
    float* __restrict__ node,
    const u16* __restrict__ wt1, const u16* __restrict__ wt2, const u16* __restrict__ wt3,
    const float* __restrict__ b1, const float* __restrict__ b2, const float* __restrict__ b3,
    int n) {
  __shared__ float ag[32][132];
  __shared__ u16 wbuf[3][8192];
  const int t = threadIdx.x, w = t >> 6, l = t & 63, c = l & 15, g = l >> 4;
  const int gsw = g ^ ((c >> 1) & 3);
  const int base = blockIdx.x * 32;

  int nB = base + 16*w + c; if (nB >= n) nB = n - 1;
  const float* aG = node + (size_t)nB * NH;
  float4 aC0 = *(const float4*)(aG + g*8);
  float4 aC1 = *(const float4*)(aG + g*8 + 4);

  node_stage(0, wt1, wt2, wt3, w, l, wbuf[0]);
  node_stage(1, wt1, wt2, wt3, w, l, wbuf[1]);

  // CSR gather: thread (row = t>>2, quarter = t&3) sums 32 floats
  {
    const int r = t >> 2, q = t & 3;
    const int rg = base + r;
    float s[32];
    #pragma unroll
    for (int i = 0; i < 32; ++i) s[i] = 0.f;
    if (rg < n) {
      const int eb = off[rg], ee = off[rg + 1];
      for (int ii = eb; ii < ee; ++ii) {
        const float* mp = mw + (size_t)csr[ii] * NH + q * 32;
        #pragma unroll
        for (int u = 0; u < 8; ++u) {
          const float4 x = *(const float4*)(mp + u * 4);
          s[u*4+0] += x.x; s[u*4+1] += x.y; s[u*4+2] += x.z; s[u*4+3] += x.w;
        }
      }
    }
    #pragma unroll
    for (int u = 0; u < 8; ++u)
      *(float4*)&ag[r][q*32 + u*4] = float4{s[u*4+0], s[u*4+1], s[u*4+2], s[u*4+3]};
  }

  f4v acc1[8];
  #pragma unroll
  for (int tt = 0; tt < 8; ++tt) {
    const float4 bb = *(const float4*)(b1 + 16*tt + 4*g);
    acc1[tt] = f4v{bb.x, bb.y, bb.z, bb.w};
  }
  __syncthreads();                       // prologue: ag ready + panels 0,1 resident

  const float* aL = &ag[16*w + c][0];
  const int srcA = ((g & 1) * 2) * 16 + c, srcB = srcA + 16;
  const bool sel1 = (g >> 1) != 0;

  // ---- layer 1: global passes 0..7
  #pragma unroll
  for (int p = 0; p < 8; ++p) {
    const int part = p >> 2, kc = p & 3;
    float4 aN0, aN1;
    if (p < 3) {
      aN0 = *(const float4*)(aG + (kc + 1)*32 + g*8);
      aN1 = *(const float4*)(aG + (kc + 1)*32 + g*8 + 4);
    }
    node_stage(p + 2, wt1, wt2, wt3, w, l, wbuf[(p + 2) % 3]);
    s8v h0, lo0;
    if (part == 0) {
      float v[8]; *(float4*)v = aC0; *(float4*)(v + 4) = aC1; split8(v, h0, lo0);
    } else {
      float v[8];
      *(float4*)v       = *(const float4*)(aL + kc*32 + g*8);
      *(float4*)(v + 4) = *(const float4*)(aL + kc*32 + g*8 + 4);
      split8(v, h0, lo0);
    }
    const u16* panel = wbuf[p % 3];
    __builtin_amdgcn_s_setprio(1);
    #pragma unroll
    for (int tt = 0; tt < 8; ++tt) {
      s8v wh, wl; wfrag(panel, tt, c, gsw, wh, wl);
      acc1[tt] = mfma3(wh, wl, h0, lo0, acc1[tt]);
    }
    __builtin_amdgcn_s_setprio(0);
    PASS_SYNC_NODE(p, 15);
    if (p < 3) { aC0 = aN0; aC1 = aN1; }
  }

  // ---- layer 2: global passes 8..11
  f4v acc2[8];
  #pragma unroll
  for (int tt = 0; tt < 8; ++tt) {
    const float4 bb = *(const float4*)(b2 + 16*tt + 4*g);
    acc2[tt] = f4v{bb.x, bb.y, bb.z, bb.w};
  }
  #pragma unroll
  for (int kc = 0; kc < 4; ++kc) {
    const int p = 8 + kc;
    node_stage(p + 2, wt1, wt2, wt3, w, l, wbuf[(p + 2) % 3]);
    s8v h0, lo0;
    trans_frag(acc1[2*kc], acc1[2*kc+1], srcA, srcB, sel1, h0, lo0);
    const u16* panel = wbuf[p % 3];
    __builtin_amdgcn_s_setprio(1);
    #pragma unroll
    for (int tt = 0; tt < 8; ++tt) {
      s8v wh, wl; wfrag(panel, tt, c, gsw, wh, wl);
      acc2[tt] = mfma3(wh, wl, h0, lo0, acc2[tt]);
    }
    __builtin_amdgcn_s_setprio(0);
    PASS_SYNC_NODE(p, 15);
  }

  // ---- layer 3: global passes 12..15 (natural)
  f4v acc3[8];
  #pragma unroll
  for (int tt = 0; tt < 8; ++tt) {
    const float bv = b3[16*tt + c];
    acc3[tt] = f4v{bv, bv, bv, bv};
  }
  #pragma unroll
  for (int kc = 0; kc < 4; ++kc) {
    const int p = 12 + kc;
    if (kc < 2) node_stage(p + 2, wt1, wt2, wt3, w, l, wbuf[(p + 2) % 3]);
    s8v h0, lo0;
    trans_frag(acc2[2*kc], acc2[2*kc+1], srcA, srcB, sel1, h0, lo0);
    const u16* panel = wbuf[p % 3];
    __builtin_amdgcn_s_setprio(1);
    #pragma unroll
    for (int tt = 0; tt < 8; ++tt) {
      s8v wh, wl; wfrag(panel, tt, c, gsw, wh, wl);
      acc3[tt] = mfma3(h0, lo0, wh, wl, acc3[tt]);
    }
    __builtin_amdgcn_s_setprio(0);
    if (p < 15) PASS_SYNC_NODE(p, 15);
  }
  __syncthreads();                       // wbuf free for transpose scratch

  // ---- transposed epilogue: node += m via coalesced float4 RMW
  float* slice = ((float*)&wbuf[0][0]) + w * 2048;
  #pragma unroll
  for (int tt = 0; tt < 8; ++tt)
    #pragma unroll
    for (int r = 0; r < 4; ++r) {
      const int row = 4*g + r;
      slice[row*128 + (((tt ^ (row & 7)) << 4) | c)] = acc3[tt][r];
    }
  __syncthreads();
  const int rowr = l >> 2, q = l & 3;
  const int e = base + 16*w + rowr;
  if (e < n) {
    float* np = node + (size_t)e * NH + q * 32;
    #pragma unroll
    for (int j = 0; j < 2; ++j)
      #pragma unroll
      for (int v = 0; v < 4; ++v) {
        const float4 m4 = *(const float4*)&slice[rowr*128 + (((2*q + j) ^ (rowr & 7)) << 4) + v*4];
        float4 x = *(const float4*)(np + j*16 + v*4);
        x.x += m4.x; x.y += m4.y; x.z += m4.z; x.w += m4.w;
        *(float4*)(np + j*16 + v*4) = x;
      }
  }
}

// ---------------- host launcher ----------------

extern "C" void kernel_launch(void* const* d_in, const int* in_sizes, int n_in,
                              void* d_out, int out_size, void* d_ws, size_t ws_size,
                              hipStream_t stream) {
  const int n = in_sizes[0];
  const int E = in_sizes[3];
  const int* xt      = (const int*)d_in[0];
  const int* ei      = (const int*)d_in[1];
  const float* eattr = (const float*)d_in[2];
  const float* dist  = (const float*)d_in[3];
  const float* embed = (const float*)d_in[4];
  const float* niW1 = (const float*)d_in[5];  const float* nib1 = (const float*)d_in[6];
  const float* niW2 = (const float*)d_in[7];  const float* nib2 = (const float*)d_in[8];
  const float* niW3 = (const float*)d_in[9];  const float* nib3 = (const float*)d_in[10];
  const float* eiW1 = (const float*)d_in[11]; const float* eib1 = (const float*)d_in[12];
  const float* eiW2 = (const float*)d_in[13]; const float* eib2 = (const float*)d_in[14];
  const float* eiW3 = (const float*)d_in[15]; const float* eib3 = (const float*)d_in[16];
  const float* noW1 = (const float*)d_in[17]; const float* nob1 = (const float*)d_in[18];
  const float* noW2 = (const float*)d_in[19]; const float* nob2 = (const float*)d_in[20];
  const float* noW3 = (const float*)d_in[21]; const float* nob3 = (const float*)d_in[22];
  const float* meW1 = (const float*)d_in[23]; const float* meb1 = (const float*)d_in[24];
  const float* meW2 = (const float*)d_in[25]; const float* meb2 = (const float*)d_in[26];
  const float* meW3 = (const float*)d_in[27]; const float* meb3 = (const float*)d_in[28];
  const float* mnW1 = (const float*)d_in[29]; const float* mnb1 = (const float*)d_in[30];
  const float* mnW2 = (const float*)d_in[31]; const float* mnb2 = (const float*)d_in[32];
  const float* mnW3 = (const float*)d_in[33]; const float* mnb3 = (const float*)d_in[34];

  float* out = (float*)d_out;
  const size_t fn = (size_t)n * NH;
  const size_t fe = (size_t)E * NH;

  float* node = (float*)d_ws;
  float* edge = node + fn;
  float* mw   = edge + fe;
  u16*   wt   = (u16*)(mw + fe);
  int*   off  = (int*)(wt + WT_TOTAL);
  int*   cur  = off + (n + 1);
  int*   csr  = cur + n;

  const int nb32   = (n + 31) / 32;
  const int nb64e  = (E + 63) / 64;
  const int nb128e = (E + 127) / 128;

  // weight prep (transpose + bf16 hi/lo split)
  k_prep<<<(PREP_ELEMS + 255) / 256, 256, 0, stream>>>(meW1, meW2, meW3, mnW1, mnW2, mnW3, wt);

  // CSR build
  hipMemsetAsync(cur, 0, (size_t)n * sizeof(int), stream);
  k_deg <<<(E + 255) / 256, 256, 0, stream>>>(ei + E, cur, E);
  k_scan<<<1, 256, 0, stream>>>(cur, off, n, E);
  k_fill<<<(E + 255) / 256, 256, 0, stream>>>(ei + E, cur, csr, E);

  // encoders
  k_enc_node<<<nb32,  TPB, 0, stream>>>(xt, embed, niW1, nib1, niW2, nib2, niW3, nib3, node, n);
  k_enc_edge<<<nb64e, TPB, 0, stream>>>(eattr, eiW1, eib1, eiW2, eib2, eiW3, eib3, edge, E);

  for (int l = 0; l < 10; ++l) {
    k_msg_mm<<<nb128e, TPB, 0, stream>>>(ei, node, edge, dist, mw,
        wt + ME1_OFF + (size_t)l * 98304,
        wt + ME2_OFF + (size_t)l * 32768,
        wt + ME3_OFF + (size_t)l * 32768,
        meb1 + (size_t)l * NH, meb2 + (size_t)l * NH, meb3 + (size_t)l * NH, E);
    k_node_mm<<<nb32, 128, 0, stream>>>(off, csr, mw, node,
        wt + MN1_OFF + (size_t)l * 65536,
        wt + MN2_OFF + (size_t)l * 32768,
        wt + MN3_OFF + (size_t)l * 32768,
        mnb1 + (size_t)l * NH, mnb2 + (size_t)l * NH, mnb3 + (size_t)l * NH, n);
  }

  k_dec<<<nb32, TPB, 0, stream>>>(node, noW1, nob1, noW2, nob2, noW3, nob3, out, n);
}

// Round 8
// 1405.297 us; speedup vs baseline: 1.2586x; 1.2586x over previous
//
#include <hip/hip_runtime.h>

// PosLearnedSimulator — split-bf16 MFMA, 16 edges/wave (occupancy-first), 3-deep async
// panel pipeline (counted vmcnt), transposed coalesced epilogues, CSR aggregation.
// N=10000 nodes, E=80000 edges, H=128, L=10 layers.

#define NH  128
#define TPB 256

typedef unsigned short u16;
typedef unsigned int   u32;
using s8v = __attribute__((ext_vector_type(8))) short;   // 8 bf16 (4 VGPR)
using f4v = __attribute__((ext_vector_type(4))) float;   // MFMA accumulator

// ---------------- bf16 split helpers ----------------

__device__ __forceinline__ u16 bf_hi(float v) {
  u32 u = __float_as_uint(v);
  return (u16)((u + 0x7FFFu + ((u >> 16) & 1u)) >> 16);   // RTNE
}
__device__ __forceinline__ float bf_f(u16 h) { return __uint_as_float((u32)h << 16); }
__device__ __forceinline__ void split2(float v, u16& h, u16& l) {
  h = bf_hi(v); l = bf_hi(v - bf_f(h));
}
__device__ __forceinline__ void split8(const float* v, s8v& fh, s8v& fl) {
  union { u32 u[4]; s8v s; } H, L;
  #pragma unroll
  for (int i = 0; i < 4; ++i) {
    u16 h0, l0, h1, l1;
    split2(v[2*i], h0, l0); split2(v[2*i+1], h1, l1);
    H.u[i] = (u32)h0 | ((u32)h1 << 16);
    L.u[i] = (u32)l0 | ((u32)l1 << 16);
  }
  fh = H.s; fl = L.s;
}

// 3-term split-bf16 MFMA: C += Ah*Bh + Ah*Bl + Al*Bh
__device__ __forceinline__ f4v mfma3(s8v ah, s8v al, s8v bh, s8v bl, f4v c) {
  c = __builtin_amdgcn_mfma_f32_16x16x32_bf16(ah, bh, c, 0, 0, 0);
  c = __builtin_amdgcn_mfma_f32_16x16x32_bf16(ah, bl, c, 0, 0, 0);
  c = __builtin_amdgcn_mfma_f32_16x16x32_bf16(al, bh, c, 0, 0, 0);
  return c;
}

__device__ __forceinline__ float lrelu(float v) { return v > 0.f ? v : 0.01f * v; }

__device__ __forceinline__ void pack2(f4v a, u32& w0, u32& w1, u32& v0, u32& v1) {
  u16 h[4], lo[4];
  #pragma unroll
  for (int r = 0; r < 4; ++r) { const float x = lrelu(a[r]); split2(x, h[r], lo[r]); }
  w0 = (u32)h[0]  | ((u32)h[1]  << 16); w1 = (u32)h[2]  | ((u32)h[3]  << 16);
  v0 = (u32)lo[0] | ((u32)lo[1] << 16); v1 = (u32)lo[2] | ((u32)lo[3] << 16);
}

__device__ __forceinline__ void trans_frag(f4v a0, f4v a1, int srcA, int srcB, bool sel1,
                                           s8v& fh, s8v& fl) {
  u32 h00,h01,l00,l01, h10,h11,l10,l11;
  pack2(a0, h00,h01,l00,l01);
  pack2(a1, h10,h11,l10,l11);
  union { u32 u[4]; s8v s; } H, L;
  u32 x, y;
  x = __shfl((int)h00, srcA); y = __shfl((int)h10, srcA); H.u[0] = sel1 ? y : x;
  x = __shfl((int)h01, srcA); y = __shfl((int)h11, srcA); H.u[1] = sel1 ? y : x;
  x = __shfl((int)h00, srcB); y = __shfl((int)h10, srcB); H.u[2] = sel1 ? y : x;
  x = __shfl((int)h01, srcB); y = __shfl((int)h11, srcB); H.u[3] = sel1 ? y : x;
  x = __shfl((int)l00, srcA); y = __shfl((int)l10, srcA); L.u[0] = sel1 ? y : x;
  x = __shfl((int)l01, srcA); y = __shfl((int)l11, srcA); L.u[1] = sel1 ? y : x;
  x = __shfl((int)l00, srcB); y = __shfl((int)l10, srcB); L.u[2] = sel1 ? y : x;
  x = __shfl((int)l01, srcB); y = __shfl((int)l11, srcB); L.u[3] = sel1 ? y : x;
  fh = H.s; fl = L.s;
}

// ---------------- async LDS weight-panel staging (global_load_lds) ----------------
// Panel: [128 rows][32 k] u16 per plane (hi at 0, lo at +4096 u16).
// Physical 16B chunk of (row, logical chunk g): slot = g ^ ((row>>1)&3); LDS dest LINEAR
// (wave-uniform base + lane*16B), source pre-swizzled.

__device__ __forceinline__ void gl_lds16(const void* g, void* l) {
  __builtin_amdgcn_global_load_lds(
      (const __attribute__((address_space(1))) void*)g,
      (__attribute__((address_space(3))) void*)l, 16, 0, 0);
}

// 256-thread variant: 4 loads/thread/panel
__device__ __forceinline__ void stage_async(const u16* __restrict__ base, int KW, int LO,
                                            int col, int w, int l, u16* wb) {
  const int glog8 = ((l & 3) ^ ((l >> 3) & 3)) * 8;
  #pragma unroll
  for (int i = 0; i < 2; ++i) {
    const int t2u = (w * 2 + i) * 64;
    const u16* gp = base + (size_t)((t2u + l) >> 2) * KW + col + glog8;
    gl_lds16(gp,      wb + (size_t)t2u * 8);
    gl_lds16(gp + LO, wb + 4096 + (size_t)t2u * 8);
  }
}

// 128-thread variant: 8 loads/thread/panel
__device__ __forceinline__ void stage_async_node(const u16* __restrict__ base, int KW, int LO,
                                                 int col, int w, int l, u16* wb) {
  const int glog8 = ((l & 3) ^ ((l >> 3) & 3)) * 8;
  #pragma unroll
  for (int i = 0; i < 4; ++i) {
    const int t2u = (w * 4 + i) * 64;
    const u16* gp = base + (size_t)((t2u + l) >> 2) * KW + col + glog8;
    gl_lds16(gp,      wb + (size_t)t2u * 8);
    gl_lds16(gp + LO, wb + 4096 + (size_t)t2u * 8);
  }
}

__device__ __forceinline__ void wfrag(const u16* panel, int tt, int c, int gsw, s8v& wh, s8v& wl) {
  const u16* p = panel + (16*tt + c) * 32 + gsw * 8;
  wh = *(const s8v*)p;
  wl = *(const s8v*)(p + 4096);
}

// end-of-pass sync: counted vmcnt keeps next-next panel in flight across the barrier
#define PASS_SYNC_MSG(p, LAST) \
  do { \
    if ((p) <= (LAST) - 2) { asm volatile("s_waitcnt vmcnt(4)" ::: "memory"); } \
    else if ((p) == (LAST) - 1) { asm volatile("s_waitcnt vmcnt(0)" ::: "memory"); } \
    __builtin_amdgcn_s_barrier(); \
    __builtin_amdgcn_sched_barrier(0); \
  } while (0)

#define PASS_SYNC_NODE(p, LAST) \
  do { \
    if ((p) <= (LAST) - 2) { asm volatile("s_waitcnt vmcnt(8)" ::: "memory"); } \
    else if ((p) == (LAST) - 1) { asm volatile("s_waitcnt vmcnt(0)" ::: "memory"); } \
    __builtin_amdgcn_s_barrier(); \
    __builtin_amdgcn_sched_barrier(0); \
  } while (0)

// ---------------- weight prep: transpose + bf16 split ----------------
#define ME1_OFF 0
#define ME2_OFF 983040
#define ME3_OFF 1310720
#define MN1_OFF 1638400
#define MN2_OFF 2293760
#define MN3_OFF 2621440
#define WT_TOTAL 2949120
#define PREP_ELEMS 1474560

__global__ void __launch_bounds__(256) k_prep(
    const float* __restrict__ meW1, const float* __restrict__ meW2, const float* __restrict__ meW3,
    const float* __restrict__ mnW1, const float* __restrict__ mnW2, const float* __restrict__ mnW3,
    u16* __restrict__ wt) {
  const int id = blockIdx.x * 256 + threadIdx.x;
  if (id >= PREP_ELEMS) return;
  const int l = id / 147456;
  const int rem = id % 147456;
  const float* src; u16* dh; int K, loc;
  if (rem < 49152)       { loc = rem;          K = 384; src = meW1 + (size_t)l*49152; dh = wt + ME1_OFF + (size_t)l*98304; }
  else if (rem < 65536)  { loc = rem - 49152;  K = 128; src = meW2 + (size_t)l*16384; dh = wt + ME2_OFF + (size_t)l*32768; }
  else if (rem < 81920)  { loc = rem - 65536;  K = 128; src = meW3 + (size_t)l*16384; dh = wt + ME3_OFF + (size_t)l*32768; }
  else if (rem < 114688) { loc = rem - 81920;  K = 256; src = mnW1 + (size_t)l*32768; dh = wt + MN1_OFF + (size_t)l*65536; }
  else if (rem < 131072) { loc = rem - 114688; K = 128; src = mnW2 + (size_t)l*16384; dh = wt + MN2_OFF + (size_t)l*32768; }
  else                   { loc = rem - 131072; K = 128; src = mnW3 + (size_t)l*16384; dh = wt + MN3_OFF + (size_t)l*32768; }
  const int n = loc / K, k = loc % K;
  const float v = src[(size_t)k * NH + n];
  u16 h, lo; split2(v, h, lo);
  dh[(size_t)n * K + k] = h;
  dh[(size_t)NH * K + (size_t)n * K + k] = lo;
}

// ---------------- CSR build ----------------

__global__ void __launch_bounds__(256) k_deg(const int* __restrict__ dst, int* __restrict__ cnt, int E) {
  const int e = blockIdx.x * 256 + threadIdx.x;
  if (e < E) atomicAdd(&cnt[dst[e]], 1);
}

__global__ void __launch_bounds__(256) k_scan(int* __restrict__ cur, int* __restrict__ off, int n, int E) {
  __shared__ int ps[256];
  const int t = threadIdx.x;
  const int chunk = (n + 255) / 256;
  const int b0 = t * chunk;
  int s = 0;
  for (int j = 0; j < chunk; ++j) { const int r = b0 + j; if (r < n) s += cur[r]; }
  ps[t] = s; __syncthreads();
  for (int d = 1; d < 256; d <<= 1) {
    const int v = (t >= d) ? ps[t - d] : 0; __syncthreads();
    ps[t] += v; __syncthreads();
  }
  int run = ps[t] - s;
  for (int j = 0; j < chunk; ++j) {
    const int r = b0 + j;
    if (r < n) { const int d = cur[r]; off[r] = run; cur[r] = run; run += d; }
  }
  if (t == 0) off[n] = E;
}

__global__ void __launch_bounds__(256) k_fill(const int* __restrict__ dst, int* __restrict__ cur,
                                              int* __restrict__ csr, int E) {
  const int e = blockIdx.x * 256 + threadIdx.x;
  if (e < E) { const int p = atomicAdd(&cur[dst[e]], 1); csr[p] = e; }
}

// ---------------- fp32 helpers for one-shot kernels (enc/dec) ----------------

__device__ __forceinline__ int swzB(int c) { return c ^ ((c >> 3) & 1); }
__device__ __forceinline__ void fma8(float* a, float s, const float4 b0, const float4 b1) {
  a[0] += s * b0.x; a[1] += s * b0.y; a[2] += s * b0.z; a[3] += s * b0.w;
  a[4] += s * b1.x; a[5] += s * b1.y; a[6] += s * b1.z; a[7] += s * b1.w;
}

template<int RB>
__device__ __forceinline__ void stage_rows128(
    const float* __restrict__ src, int row_base, int nmax, float* As, int t) {
  const int c = t & 31;
  for (int e = t >> 5; e < RB; e += 8) {
    int r = row_base + e; if (r >= nmax) r = nmax - 1;
    const float4 v = reinterpret_cast<const float4*>(src + (size_t)r * NH)[c];
    reinterpret_cast<float4*>(As)[e * 32 + (c ^ ((e >> 2) & 7))] = v;
  }
}

template<int RB>
__device__ __forceinline__ void stage_smallK(
    const float* __restrict__ src, const int* __restrict__ ridx,
    int row_base, int nmax, int F, float* As, int t) {
  for (int i = t; i < RB * F; i += TPB) {
    const int e = i / F, f = i - e * F;
    int r;
    if (ridx) r = ridx[e];
    else { r = row_base + e; if (r >= nmax) r = nmax - 1; }
    As[e * NH + ((((f >> 2) ^ ((e >> 2) & 7)) << 2) | (f & 3))] = src[(size_t)r * F + f];
  }
}

template<int AR>
__device__ __forceinline__ void init_acc(const float* __restrict__ b, float acc[AR][8], int t) {
  const int o0 = (t >> 4) * 8;
  const float4 c0 = *reinterpret_cast<const float4*>(b + o0);
  const float4 c1 = *reinterpret_cast<const float4*>(b + o0 + 4);
  #pragma unroll
  for (int i = 0; i < AR; ++i) {
    acc[i][0] = c0.x; acc[i][1] = c0.y; acc[i][2] = c0.z; acc[i][3] = c0.w;
    acc[i][4] = c1.x; acc[i][5] = c1.y; acc[i][6] = c1.z; acc[i][7] = c1.w;
  }
}

template<int AR>
__device__ __forceinline__ void gemm_block(
    const float* __restrict__ W, int Kpart,
    const float* As, float* Bs, float acc[AR][8], int t) {
  const int e0  = (t & 15) * AR;
  const int g   = t >> 4;
  const int ob0 = swzB(g * 2) * 4;
  const int ob1 = swzB(g * 2 + 1) * 4;
  int sr[AR];
  #pragma unroll
  for (int i = 0; i < AR; ++i) sr[i] = ((e0 + i) >> 2) & 7;
  for (int sub = 0; sub < Kpart; sub += 32) {
    int kmax = Kpart - sub; if (kmax > 32) kmax = 32;
    __syncthreads();
    {
      const int r  = t >> 3;
      const int cb = (t & 7) * 4;
      if (r < kmax) {
        const float4* s4 = reinterpret_cast<const float4*>(W + (size_t)(sub + r) * NH) + cb;
        #pragma unroll
        for (int j = 0; j < 4; ++j)
          *reinterpret_cast<float4*>(Bs + r * NH + swzB(cb + j) * 4) = s4[j];
      }
    }
    __syncthreads();
    if (kmax == 32) {
      #pragma unroll
      for (int k4 = 0; k4 < 8; ++k4) {
        const int gch = (sub >> 2) + k4;
        float4 aa[AR];
        #pragma unroll
        for (int i = 0; i < AR; ++i)
          aa[i] = reinterpret_cast<const float4*>(As)[(e0 + i) * 32 + (gch ^ sr[i])];
        #pragma unroll
        for (int kk = 0; kk < 4; ++kk) {
          const int k = k4 * 4 + kk;
          const float4 b0 = *reinterpret_cast<const float4*>(Bs + k * NH + ob0);
          const float4 b1 = *reinterpret_cast<const float4*>(Bs + k * NH + ob1);
          #pragma unroll
          for (int i = 0; i < AR; ++i) {
            const float a = (kk == 0) ? aa[i].x : (kk == 1) ? aa[i].y : (kk == 2) ? aa[i].z : aa[i].w;
            fma8(acc[i], a, b0, b1);
          }
        }
      }
    } else {
      for (int k = 0; k < kmax; ++k) {
        const int kk = sub + k;
        const float4 b0 = *reinterpret_cast<const float4*>(Bs + k * NH + ob0);
        const float4 b1 = *reinterpret_cast<const float4*>(Bs + k * NH + ob1);
        #pragma unroll
        for (int i = 0; i < AR; ++i) {
          const float a = As[(e0 + i) * NH + ((((kk >> 2) ^ sr[i]) << 2) | (kk & 3))];
          fma8(acc[i], a, b0, b1);
        }
      }
    }
  }
}

template<int AR, bool ACT>
__device__ __forceinline__ void act_store(float* As, float acc[AR][8], int t) {
  const int e0 = (t & 15) * AR;
  const int g  = t >> 4;
  __syncthreads();
  #pragma unroll
  for (int i = 0; i < AR; ++i) {
    const int r = e0 + i;
    const int s = (r >> 2) & 7;
    float v[8];
    #pragma unroll
    for (int j = 0; j < 8; ++j) v[j] = ACT ? lrelu(acc[i][j]) : acc[i][j];
    float4 w0 = {v[0], v[1], v[2], v[3]};
    float4 w1 = {v[4], v[5], v[6], v[7]};
    reinterpret_cast<float4*>(As + r * NH)[(g * 2)     ^ s] = w0;
    reinterpret_cast<float4*>(As + r * NH)[(g * 2 + 1) ^ s] = w1;
  }
  __syncthreads();
}

// ---------------- encoders / decoder (fp32, one-shot) ----------------

__global__ void __launch_bounds__(TPB) k_enc_node(
    const int* __restrict__ xt, const float* __restrict__ embed,
    const float* __restrict__ W1, const float* __restrict__ b1,
    const float* __restrict__ W2, const float* __restrict__ b2,
    const float* __restrict__ W3, const float* __restrict__ b3,
    float* __restrict__ node, int n) {
  constexpr int RB = 32, AR = 2;
  __shared__ float As[RB * NH];
  __shared__ float Bs[32 * NH];
  __shared__ int rid[RB];
  const int t = threadIdx.x;
  const int base = blockIdx.x * RB;
  if (t < RB) { int r = base + t; if (r >= n) r = n - 1; rid[t] = xt[r]; }
  __syncthreads();
  stage_smallK<RB>(embed, rid, 0, 2, 7, As, t);
  float acc[AR][8];
  init_acc<AR>(b1, acc, t);
  gemm_block<AR>(W1, 7, As, Bs, acc, t);
  act_store<AR, true>(As, acc, t);
  init_acc<AR>(b2, acc, t);
  gemm_block<AR>(W2, NH, As, Bs, acc, t);
  act_store<AR, true>(As, acc, t);
  init_acc<AR>(b3, acc, t);
  gemm_block<AR>(W3, NH, As, Bs, acc, t);
  const int e0 = (t & 15) * AR, o0 = (t >> 4) * 8;
  #pragma unroll
  for (int i = 0; i < AR; ++i) {
    const int r = base + e0 + i;
    if (r < n) {
      float4 v0 = {acc[i][0], acc[i][1], acc[i][2], acc[i][3]};
      float4 v1 = {acc[i][4], acc[i][5], acc[i][6], acc[i][7]};
      float4* p = reinterpret_cast<float4*>(node + (size_t)r * NH + o0);
      p[0] = v0; p[1] = v1;
    }
  }
}

__global__ void __launch_bounds__(TPB) k_enc_edge(
    const float* __restrict__ ea,
    const float* __restrict__ W1, const float* __restrict__ b1,
    const float* __restrict__ W2, const float* __restrict__ b2,
    const float* __restrict__ W3, const float* __restrict__ b3,
    float* __restrict__ edge, int nE) {
  constexpr int RB = 64, AR = 4;
  __shared__ float As[RB * NH];
  __shared__ float Bs[32 * NH];
  const int t = threadIdx.x;
  const int base = blockIdx.x * RB;
  stage_smallK<RB>(ea, nullptr, base, nE, 21, As, t);
  float acc[AR][8];
  init_acc<AR>(b1, acc, t);
  gemm_block<AR>(W1, 21, As, Bs, acc, t);
  act_store<AR, true>(As, acc, t);
  init_acc<AR>(b2, acc, t);
  gemm_block<AR>(W2, NH, As, Bs, acc, t);
  act_store<AR, true>(As, acc, t);
  init_acc<AR>(b3, acc, t);
  gemm_block<AR>(W3, NH, As, Bs, acc, t);
  const int e0 = (t & 15) * AR, o0 = (t >> 4) * 8;
  #pragma unroll
  for (int i = 0; i < AR; ++i) {
    const int r = base + e0 + i;
    if (r < nE) {
      float4 v0 = {acc[i][0], acc[i][1], acc[i][2], acc[i][3]};
      float4 v1 = {acc[i][4], acc[i][5], acc[i][6], acc[i][7]};
      float4* p = reinterpret_cast<float4*>(edge + (size_t)r * NH + o0);
      p[0] = v0; p[1] = v1;
    }
  }
}

__global__ void __launch_bounds__(TPB) k_dec(
    const float* __restrict__ node,
    const float* __restrict__ W1, const float* __restrict__ b1,
    const float* __restrict__ W2, const float* __restrict__ b2,
    const float* __restrict__ W3, const float* __restrict__ b3,
    float* __restrict__ out, int n) {
  constexpr int RB = 32, AR = 2;
  __shared__ float As[RB * NH];
  __shared__ float Bs[32 * NH];
  const int t = threadIdx.x;
  const int base = blockIdx.x * RB;
  stage_rows128<RB>(node, base, n, As, t);
  float acc[AR][8];
  init_acc<AR>(b1, acc, t);
  gemm_block<AR>(W1, NH, As, Bs, acc, t);
  act_store<AR, true>(As, acc, t);
  init_acc<AR>(b2, acc, t);
  gemm_block<AR>(W2, NH, As, Bs, acc, t);
  act_store<AR, true>(As, acc, t);
  if (t < RB * 2) {
    const int e = t >> 1, oc = t & 1;
    const int r = base + e;
    if (r < n) {
      const int s = (e >> 2) & 7;
      float sum = b3[oc];
      #pragma unroll 8
      for (int k = 0; k < NH; ++k)
        sum += As[e * NH + ((((k >> 2) ^ s) << 2) | (k & 3))] * W3[k * 2 + oc];
      out[(size_t)r * 2 + oc] = sum;
    }
  }
}

// ---------------- MFMA message kernel (v6: 16 edges/wave, 64 edges/block) ----------------
__device__ __forceinline__ void msg_stage(int p, const u16* wt1, const u16* wt2, const u16* wt3,
                                          int w, int l, u16* dst) {
  if (p < 12)      stage_async(wt1, 384, 49152, p * 32, w, l, dst);
  else if (p < 16) stage_async(wt2, 128, 16384, (p - 12) * 32, w, l, dst);
  else             stage_async(wt3, 128, 16384, (p - 16) * 32, w, l, dst);
}

__global__ void __launch_bounds__(TPB) k_msg_mm(
    const int* __restrict__ ei, const float* __restrict__ node,
    float* __restrict__ edge, const float* __restrict__ dist, float* __restrict__ mw,
    const u16* __restrict__ wt1, const u16* __restrict__ wt2, const u16* __restrict__ wt3,
    const float* __restrict__ b1, const float* __restrict__ b2, const float* __restrict__ b3,
    int E) {
  __shared__ u16 wbuf[3][8192];
  const int t = threadIdx.x, w = t >> 6, l = t & 63, c = l & 15, g = l >> 4;
  const int gsw = g ^ ((c >> 1) & 3);
  const int wbase = blockIdx.x * 64 + w * 16;
  int e0 = wbase + c;
  if (e0 >= E) e0 = E - 1;
  const int sj0 = ei[e0], di0 = ei[E + e0];

  const float* ap0[3] = { node + (size_t)di0 * NH, node + (size_t)sj0 * NH, edge + (size_t)e0 * NH };

  // acts for pass 0, then panels 0 and 1 async
  float4 aC0 = *(const float4*)(ap0[0] + g*8);
  float4 aC1 = *(const float4*)(ap0[0] + g*8 + 4);
  stage_async(wt1, 384, 49152, 0,  w, l, wbuf[0]);
  stage_async(wt1, 384, 49152, 32, w, l, wbuf[1]);

  f4v acc1[8];
  #pragma unroll
  for (int tt = 0; tt < 8; ++tt) {
    const float4 bb = *(const float4*)(b1 + 16*tt + 4*g);
    acc1[tt] = f4v{bb.x, bb.y, bb.z, bb.w};
  }
  __syncthreads();                       // prologue: full drain (panels 0,1 resident)

  const int srcA = ((g & 1) * 2) * 16 + c, srcB = srcA + 16;
  const bool sel1 = (g >> 1) != 0;

  // ---- layer 1 (transposed): global passes 0..11
  #pragma unroll
  for (int p = 0; p < 12; ++p) {
    float4 aN0, aN1;
    if (p < 11) {                        // acts for p+1 (issued before stage -> older)
      const int pt = (p + 1) >> 2, kn = (p + 1) & 3;
      aN0 = *(const float4*)(ap0[pt] + kn*32 + g*8);
      aN1 = *(const float4*)(ap0[pt] + kn*32 + g*8 + 4);
    }
    msg_stage(p + 2, wt1, wt2, wt3, w, l, wbuf[(p + 2) % 3]);
    s8v h0, lo0;
    { float v[8];
      *(float4*)v = aC0; *(float4*)(v + 4) = aC1; split8(v, h0, lo0); }
    const u16* panel = wbuf[p % 3];
    __builtin_amdgcn_s_setprio(1);
    #pragma unroll
    for (int tt = 0; tt < 8; ++tt) {
      s8v wh, wl; wfrag(panel, tt, c, gsw, wh, wl);
      acc1[tt] = mfma3(wh, wl, h0, lo0, acc1[tt]);
    }
    __builtin_amdgcn_s_setprio(0);
    PASS_SYNC_MSG(p, 19);
    if (p < 11) { aC0 = aN0; aC1 = aN1; }
  }

  // ---- layer 2 (transposed): global passes 12..15
  f4v acc2[8];
  #pragma unroll
  for (int tt = 0; tt < 8; ++tt) {
    const float4 bb = *(const float4*)(b2 + 16*tt + 4*g);
    acc2[tt] = f4v{bb.x, bb.y, bb.z, bb.w};
  }
  #pragma unroll
  for (int kc = 0; kc < 4; ++kc) {
    const int p = 12 + kc;
    msg_stage(p + 2, wt1, wt2, wt3, w, l, wbuf[(p + 2) % 3]);
    s8v h0, lo0;
    trans_frag(acc1[2*kc], acc1[2*kc+1], srcA, srcB, sel1, h0, lo0);
    const u16* panel = wbuf[p % 3];
    __builtin_amdgcn_s_setprio(1);
    #pragma unroll
    for (int tt = 0; tt < 8; ++tt) {
      s8v wh, wl; wfrag(panel, tt, c, gsw, wh, wl);
      acc2[tt] = mfma3(wh, wl, h0, lo0, acc2[tt]);
    }
    __builtin_amdgcn_s_setprio(0);
    PASS_SYNC_MSG(p, 19);
  }

  // ---- layer 3 (natural): global passes 16..19
  f4v acc3[8];
  #pragma unroll
  for (int tt = 0; tt < 8; ++tt) {
    const float bv = b3[16*tt + c];
    acc3[tt] = f4v{bv, bv, bv, bv};
  }
  #pragma unroll
  for (int kc = 0; kc < 4; ++kc) {
    const int p = 16 + kc;
    if (kc < 2) msg_stage(p + 2, wt1, wt2, wt3, w, l, wbuf[(p + 2) % 3]);
    s8v h0, lo0;
    trans_frag(acc2[2*kc], acc2[2*kc+1], srcA, srcB, sel1, h0, lo0);
    const u16* panel = wbuf[p % 3];
    __builtin_amdgcn_s_setprio(1);
    #pragma unroll
    for (int tt = 0; tt < 8; ++tt) {
      s8v wh, wl; wfrag(panel, tt, c, gsw, wh, wl);
      acc3[tt] = mfma3(h0, lo0, wh, wl, acc3[tt]);
    }
    __builtin_amdgcn_s_setprio(0);
    if (p < 19) PASS_SYNC_MSG(p, 19);
  }
  __syncthreads();                       // wbuf free for transpose scratch

  // ---- transposed epilogue: m through per-wave LDS slice -> coalesced float4 RMW/stores
  float* slice = ((float*)&wbuf[0][0]) + w * 2048;      // per-wave 16 rows x 128 f32
  #pragma unroll
  for (int tt = 0; tt < 8; ++tt)
    #pragma unroll
    for (int r = 0; r < 4; ++r) {
      const int row = 4*g + r;
      slice[row*128 + (((tt ^ (row & 7)) << 4) | c)] = acc3[tt][r];
    }
  // same-wave visibility: lgkmcnt only (no barrier needed)
  const int rowr = l >> 2, q = l & 3;
  const int e = wbase + rowr;
  if (e < E) {
    const float dw = dist[e];
    float* ep = edge + (size_t)e * NH + q * 32;
    float* mp = mw   + (size_t)e * NH + q * 32;
    #pragma unroll
    for (int j = 0; j < 2; ++j)
      #pragma unroll
      for (int v = 0; v < 4; ++v) {
        const float4 m4 = *(const float4*)&slice[rowr*128 + (((2*q + j) ^ (rowr & 7)) << 4) + v*4];
        float4 x = *(const float4*)(ep + j*16 + v*4);
        x.x += m4.x; x.y += m4.y; x.z += m4.z; x.w += m4.w;
        *(float4*)(ep + j*16 + v*4) = x;
        float4 mm = {m4.x*dw, m4.y*dw, m4.z*dw, m4.w*dw};
        *(float4*)(mp + j*16 + v*4) = mm;
      }
  }
}

// ---------------- MFMA node-update kernel (128 threads, 32 nodes, 3-deep pipeline) ----------------
__device__ __forceinline__ void node_stage(int p, const u16* wt1, const u16* wt2, const u16* wt3,
                                           int w, int l, u16* dst) {
  if (p < 8)       stage_async_node(wt1, 256, 32768, p * 32, w, l, dst);
  else if (p < 12) stage_async_node(wt2, 128, 16384, (p - 8) * 32, w, l, dst);
  else             stage_async_node(wt3, 128, 16384, (p - 12) * 32, w, l, dst);
}

__global__ void __launch_bounds__(128) k_node_mm(
    const int* __restrict__ off, const int* __restrict__ csr, const float* __restrict__ mw,
    float* __restrict__ node,
    const u16* __restrict__ wt1, const u16* __restrict__ wt2, const u16* __restrict__ wt3,
    const float* __restrict__ b1, const float* __restrict__ b2, const float* __restrict__ b3,
    int n) {
  __shared__ float ag[32][132];
  __shared__ u16 wbuf[3][8192];
  const int t = threadIdx.x, w = t >> 6, l = t & 63, c = l & 15, g = l >> 4;
  const int gsw = g ^ ((c >> 1) & 3);
  const int base = blockIdx.x * 32;

  int nB = base + 16*w + c; if (nB >= n) nB = n - 1;
  const float* aG = node + (size_t)nB * NH;
  float4 aC0 = *(const float4*)(aG + g*8);
  float4 aC1 = *(const float4*)(aG + g*8 + 4);

  node_stage(0, wt1, wt2, wt3, w, l, wbuf[0]);
  node_stage(1, wt1, wt2, wt3, w, l, wbuf[1]);

  // CSR gather: thread (row = t>>2, quarter = t&3) sums 32 floats
  {
    const int r = t >> 2, q = t & 3;
    const int rg = base + r;
    float s[32];
    #pragma unroll
    for (int i = 0; i < 32; ++i) s[i] = 0.f;
    if (rg < n) {
      const int eb = off[rg], ee = off[rg + 1];
      for (int ii = eb; ii < ee; ++ii) {
        const float* mp = mw + (size_t)csr[ii] * NH + q * 32;
        #pragma unroll
        for (int u = 0; u < 8; ++u) {
          const float4 x = *(const float4*)(mp + u * 4);
          s[u*4+0] += x.x; s[u*4+1] += x.y; s[u*4+2] += x.z; s[u*4+3] += x.w;
        }
      }
    }
    #pragma unroll
    for (int u = 0; u < 8; ++u)
      *(float4*)&ag[r][q*32 + u*4] = float4{s[u*4+0], s[u*4+1], s[u*4+2], s[u*4+3]};
  }

  f4v acc1[8];
  #pragma unroll
  for (int tt = 0; tt < 8; ++tt) {
    const float4 bb = *(const float4*)(b1 + 16*tt + 4*g);
    acc1[tt] = f4v{bb.x, bb.y, bb.z, bb.w};
  }
  __syncthreads();                       // prologue: ag ready + panels 0,1 resident

  const float* aL = &ag[16*w + c][0];
  const int srcA = ((g & 1) * 2) * 16 + c, srcB = srcA + 16;
  const bool sel1 = (g >> 1) != 0;

  // ---- layer 1: global passes 0..7
  #pragma unroll
  for (int p = 0; p < 8; ++p) {
    const int part = p >> 2, kc = p & 3;
    float4 aN0, aN1;
    if (p < 3) {
      aN0 = *(const float4*)(aG + (kc + 1)*32 + g*8);
      aN1 = *(const float4*)(aG + (kc + 1)*32 + g*8 + 4);
    }
    node_stage(p + 2, wt1, wt2, wt3, w, l, wbuf[(p + 2) % 3]);
    s8v h0, lo0;
    if (part == 0) {
      float v[8]; *(float4*)v = aC0; *(float4*)(v + 4) = aC1; split8(v, h0, lo0);
    } else {
      float v[8];
      *(float4*)v       = *(const float4*)(aL + kc*32 + g*8);
      *(float4*)(v + 4) = *(const float4*)(aL + kc*32 + g*8 + 4);
      split8(v, h0, lo0);
    }
    const u16* panel = wbuf[p % 3];
    __builtin_amdgcn_s_setprio(1);
    #pragma unroll
    for (int tt = 0; tt < 8; ++tt) {
      s8v wh, wl; wfrag(panel, tt, c, gsw, wh, wl);
      acc1[tt] = mfma3(wh, wl, h0, lo0, acc1[tt]);
    }
    __builtin_amdgcn_s_setprio(0);
    PASS_SYNC_NODE(p, 15);
    if (p < 3) { aC0 = aN0; aC1 = aN1; }
  }

  // ---- layer 2: global passes 8..11
  f4v acc2[8];
  #pragma unroll
  for (int tt = 0; tt < 8; ++tt) {
    const float4 bb = *(const float4*)(b2 + 16*tt + 4*g);
    acc2[tt] = f4v{bb.x, bb.y, bb.z, bb.w};
  }
  #pragma unroll
  for (int kc = 0; kc < 4; ++kc) {
    const int p = 8 + kc;
    node_stage(p + 2, wt1, wt2, wt3, w, l, wbuf[(p + 2) % 3]);
    s8v h0, lo0;
    trans_frag(acc1[2*kc], acc1[2*kc+1], srcA, srcB, sel1, h0, lo0);
    const u16* panel = wbuf[p % 3];
    __builtin_amdgcn_s_setprio(1);
    #pragma unroll
    for (int tt = 0; tt < 8; ++tt) {
      s8v wh, wl; wfrag(panel, tt, c, gsw, wh, wl);
      acc2[tt] = mfma3(wh, wl, h0, lo0, acc2[tt]);
    }
    __builtin_amdgcn_s_setprio(0);
    PASS_SYNC_NODE(p, 15);
  }

  // ---- layer 3: global passes 12..15 (natural)
  f4v acc3[8];
  #pragma unroll
  for (int tt = 0; tt < 8; ++tt) {
    const float bv = b3[16*tt + c];
    acc3[tt] = f4v{bv, bv, bv, bv};
  }
  #pragma unroll
  for (int kc = 0; kc < 4; ++kc) {
    const int p = 12 + kc;
    if (kc < 2) node_stage(p + 2, wt1, wt2, wt3, w, l, wbuf[(p + 2) % 3]);
    s8v h0, lo0;
    trans_frag(acc2[2*kc], acc2[2*kc+1], srcA, srcB, sel1, h0, lo0);
    const u16* panel = wbuf[p % 3];
    __builtin_amdgcn_s_setprio(1);
    #pragma unroll
    for (int tt = 0; tt < 8; ++tt) {
      s8v wh, wl; wfrag(panel, tt, c, gsw, wh, wl);
      acc3[tt] = mfma3(h0, lo0, wh, wl, acc3[tt]);
    }
    __builtin_amdgcn_s_setprio(0);
    if (p < 15) PASS_SYNC_NODE(p, 15);
  }
  __syncthreads();                       // wbuf free for transpose scratch

  // ---- transposed epilogue: node += m via coalesced float4 RMW
  float* slice = ((float*)&wbuf[0][0]) + w * 2048;
  #pragma unroll
  for (int tt = 0; tt < 8; ++tt)
    #pragma unroll
    for (int r = 0; r < 4; ++r) {
      const int row = 4*g + r;
      slice[row*128 + (((tt ^ (row & 7)) << 4) | c)] = acc3[tt][r];
    }
  const int rowr = l >> 2, q = l & 3;
  const int e = base + 16*w + rowr;
  if (e < n) {
    float* np = node + (size_t)e * NH + q * 32;
    #pragma unroll
    for (int j = 0; j < 2; ++j)
      #pragma unroll
      for (int v = 0; v < 4; ++v) {
        const float4 m4 = *(const float4*)&slice[rowr*128 + (((2*q + j) ^ (rowr & 7)) << 4) + v*4];
        float4 x = *(const float4*)(np + j*16 + v*4);
        x.x += m4.x; x.y += m4.y; x.z += m4.z; x.w += m4.w;
        *(float4*)(np + j*16 + v*4) = x;
      }
  }
}

// ---------------- host launcher ----------------

extern "C" void kernel_launch(void* const* d_in, const int* in_sizes, int n_in,
                              void* d_out, int out_size, void* d_ws, size_t ws_size,
                              hipStream_t stream) {
  const int n = in_sizes[0];
  const int E = in_sizes[3];
  const int* xt      = (const int*)d_in[0];
  const int* ei      = (const int*)d_in[1];
  const float* eattr = (const float*)d_in[2];
  const float* dist  = (const float*)d_in[3];
  const float* embed = (const float*)d_in[4];
  const float* niW1 = (const float*)d_in[5];  const float* nib1 = (const float*)d_in[6];
  const float* niW2 = (const float*)d_in[7];  const float* nib2 = (const float*)d_in[8];
  const float* niW3 = (const float*)d_in[9];  const float* nib3 = (const float*)d_in[10];
  const float* eiW1 = (const float*)d_in[11]; const float* eib1 = (const float*)d_in[12];
  const float* eiW2 = (const float*)d_in[13]; const float* eib2 = (const float*)d_in[14];
  const float* eiW3 = (const float*)d_in[15]; const float* eib3 = (const float*)d_in[16];
  const float* noW1 = (const float*)d_in[17]; const float* nob1 = (const float*)d_in[18];
  const float* noW2 = (const float*)d_in[19]; const float* nob2 = (const float*)d_in[20];
  const float* noW3 = (const float*)d_in[21]; const float* nob3 = (const float*)d_in[22];
  const float* meW1 = (const float*)d_in[23]; const float* meb1 = (const float*)d_in[24];
  const float* meW2 = (const float*)d_in[25]; const float* meb2 = (const float*)d_in[26];
  const float* meW3 = (const float*)d_in[27]; const float* meb3 = (const float*)d_in[28];
  const float* mnW1 = (const float*)d_in[29]; const float* mnb1 = (const float*)d_in[30];
  const float* mnW2 = (const float*)d_in[31]; const float* mnb2 = (const float*)d_in[32];
  const float* mnW3 = (const float*)d_in[33]; const float* mnb3 = (const float*)d_in[34];

  float* out = (float*)d_out;
  const size_t fn = (size_t)n * NH;
  const size_t fe = (size_t)E * NH;

  float* node = (float*)d_ws;
  float* edge = node + fn;
  float* mw   = edge + fe;
  u16*   wt   = (u16*)(mw + fe);
  int*   off  = (int*)(wt + WT_TOTAL);
  int*   cur  = off + (n + 1);
  int*   csr  = cur + n;

  const int nb32   = (n + 31) / 32;
  const int nb64e  = (E + 63) / 64;

  // weight prep (transpose + bf16 hi/lo split)
  k_prep<<<(PREP_ELEMS + 255) / 256, 256, 0, stream>>>(meW1, meW2, meW3, mnW1, mnW2, mnW3, wt);

  // CSR build
  hipMemsetAsync(cur, 0, (size_t)n * sizeof(int), stream);
  k_deg <<<(E + 255) / 256, 256, 0, stream>>>(ei + E, cur, E);
  k_scan<<<1, 256, 0, stream>>>(cur, off, n, E);
  k_fill<<<(E + 255) / 256, 256, 0, stream>>>(ei + E, cur, csr, E);

  // encoders
  k_enc_node<<<nb32,  TPB, 0, stream>>>(xt, embed, niW1, nib1, niW2, nib2, niW3, nib3, node, n);
  k_enc_edge<<<nb64e, TPB, 0, stream>>>(eattr, eiW1, eib1, eiW2, eib2, eiW3, eib3, edge, E);

  for (int l = 0; l < 10; ++l) {
    k_msg_mm<<<nb64e, TPB, 0, stream>>>(ei, node, edge, dist, mw,
        wt + ME1_OFF + (size_t)l * 98304,
        wt + ME2_OFF + (size_t)l * 32768,
        wt + ME3_OFF + (size_t)l * 32768,
        meb1 + (size_t)l * NH, meb2 + (size_t)l * NH, meb3 + (size_t)l * NH, E);
    k_node_mm<<<nb32, 128, 0, stream>>>(off, csr, mw, node,
        wt + MN1_OFF + (size_t)l * 65536,
        wt + MN2_OFF + (size_t)l * 32768,
        wt + MN3_OFF + (size_t)l * 32768,
        mnb1 + (size_t)l * NH, mnb2 + (size_t)l * NH, mnb3 + (size_t)l * NH, n);
  }

  k_dec<<<nb32, TPB, 0, stream>>>(node, noW1, nob1, noW2, nob2, noW3, nob3, out, n);
}